// Round 16
// baseline (162.517 us; speedup 1.0000x reference)
//
#include <hip/hip_runtime.h>

#define Bn 512
#define Cn 202
#define Pn 27
#define Nn 729
#define CHn 200
#define Kn 58
#define OUTCn 64
#define CENTERn 364    // 13*27+13
#define NCHUNK 7       // 32-ch MFMA chunks (224 padded)
#define POOLR 128      // pool rows (slots); row 127 always zero
#define ZSLOT 127
#define NCK8 28        // 8-ch pool chunks (25 real + 3 zeroed)
#define WTOT (NCHUNK * 9 * OUTCn * 32)   // 129024
#define USTDQ 9        // U row stride in dwords per o-quarter (8 data + 1 pad; odd -> full bank spread)

// ---- fat-kernel LDS layout (bytes) ----
// R region (reused): scan (sp 2916 + slotS 1458 + Mfull 1458) | stage 23,328 | U 9*128*9*4 = 41,472
#define R_BYTES 41472
#define POOL_OFF R_BYTES                       // 28*128*8 shorts = 57,344 B
#define SLOT_OFF (POOL_OFF + NCK8 * POOLR * 8 * 2)
#define MLIST_OFF (SLOT_OFF + 1684)
#define LDS_BYTES (MLIST_OFF + 256)            // ~100.8 KB -> 1 block/CU, 16 waves

typedef float f32x4 __attribute__((ext_vector_type(4)));
typedef f32x4 f32x4u __attribute__((aligned(4)));   // dword-aligned vector load
typedef short s16x8 __attribute__((ext_vector_type(8)));

static __device__ __forceinline__ unsigned short f2bf(float f) {
  unsigned u = __float_as_uint(f);
  u += 0x7fffu + ((u >> 16) & 1u);   // RNE
  return (unsigned short)(u >> 16);
}

// ---------------- Kernel W: weights -> bf16, chunked layout Wt2[ck][r][o][32] ----------------
__global__ __launch_bounds__(256) void wprep_kernel(const float* __restrict__ W,
                                                    short* __restrict__ Wt2) {
  int idx = blockIdx.x * 256 + threadIdx.x;
  if (idx >= WTOT) return;
  int ck = idx / (9 * OUTCn * 32);
  int rem = idx - ck * (9 * OUTCn * 32);
  int r = rem / (OUTCn * 32);
  int rem2 = rem - r * (OUTCn * 32);
  int o = rem2 >> 5;
  int cl = rem2 & 31;
  int cc = ck * 32 + cl;
  float v = (cc < CHn) ? W[((size_t)o * CHn + cc) * 9 + r] : 0.f;
  Wt2[idx] = (short)f2bf(v);
}

// ---------------- Kernel FAT: scan + pool-in-LDS + 4x(U-GEMM, gather, store) ----------------
// 512 blocks (1/batch) x 1024 thr = 16 waves. All global traffic streaming-coalesced;
// all random access in LDS (avoids the L2 random-transaction floor of rounds 2-6).
__global__ __launch_bounds__(1024, 4) void fat_kernel(const float* __restrict__ x,
                                                      const int* __restrict__ rand_idx,
                                                      const short* __restrict__ Wt2,
                                                      const float* __restrict__ bias,
                                                      float* __restrict__ y) {
  __shared__ __align__(16) char LB[LDS_BYTES];
  __shared__ int wsum[16];
  __shared__ int s_num;
  float* spf = (float*)LB;                    // scan: [729] f32
  short* slotS = (short*)(LB + 2916);         // scan: [729]
  short* Mfull = (short*)(LB + 2916 + 1464);  // scan: [729]
  float* stageF = (float*)LB;                 // staging: [8*729] f32
  f32x4* stage4 = (f32x4*)LB;
  unsigned* U = (unsigned*)LB;                // passes: [9*128*9] dwords
  short* Pool = (short*)(LB + POOL_OFF);      // [28][128][8] bf16
  short* Slot = (short*)(LB + SLOT_OFF);      // [841]
  short* Mlist = (short*)(LB + MLIST_OFF);    // [128]

  const int b = blockIdx.x;
  const int tid = threadIdx.x;
  const int lane = tid & 63;
  const int wv = tid >> 6;        // 0..15
  const int l16 = lane & 15;
  const int kg = lane >> 4;       // 0..3

  // zero Pool (incl. 3 pad chunks -> MFMA B side safe)
  for (int i = tid; i < NCK8 * POOLR * 8 / 2; i += 1024) ((unsigned*)Pool)[i] = 0u;

  // ---- scan: sp plane, random-idx poke, mask + prefix ----
  const float* xsp = x + ((size_t)b * Cn + CHn) * Nn;
  if (tid < Nn) spf[tid] = xsp[tid];
  __syncthreads();
  float central = spf[CENTERn];
  __syncthreads();
  if (tid < Kn) spf[rand_idx[b * Kn + tid]] = central;
  __syncthreads();

  bool mk = false;
  int cnt = 0;
  if (tid < Nn) { mk = (spf[tid] == central); cnt = mk ? 1 : 0; }
  int v = cnt;
#pragma unroll
  for (int off = 1; off < 64; off <<= 1) {
    int u2 = __shfl_up(v, off);
    if (lane >= off) v += u2;
  }
  if (lane == 63) wsum[wv] = v;
  __syncthreads();
  if (tid == 0) {
    int s = 0;
#pragma unroll
    for (int w = 0; w < 16; ++w) { int t = wsum[w]; wsum[w] = s; s += t; }
    s_num = s;
  }
  __syncthreads();
  const int num = s_num;              // >= 1 (central always masked)
  int excl = v - cnt + wsum[wv];
  if (tid < Nn) {
    if (mk) { Mfull[excl] = (short)tid; slotS[tid] = (short)excl; }
    else { slotS[tid] = (short)(~(tid - excl)); }   // zrank
  }
  __syncthreads();

  const int num1 = num < ZSLOT ? num : ZSLOT;
  if (tid < 841) {
    int pi = tid / 29, pj = tid - pi * 29;
    short val = (short)ZSLOT;
    if (pi >= 1 && pi <= 27 && pj >= 1 && pj <= 27) {
      int n = (pi - 1) * Pn + (pj - 1);
      int s0 = slotS[n];
      int sv = (s0 >= 0) ? s0 : ((~s0) % num);
      if (sv > ZSLOT - 1) sv = ZSLOT - 1;   // freak-case clamp (num>127 is +6 sigma)
      val = (short)sv;
    }
    Slot[tid] = val;
  }
  if (tid < POOLR) Mlist[tid] = (tid < num) ? Mfull[tid] : (short)0;
  __syncthreads();   // Slot/Mlist persistent; R region free

  // ---- staging loop: 25 chunks of 8 planes, register-pipelined ----
  f32x4 c0v, c1v = (f32x4){0.f, 0.f, 0.f, 0.f};
  {
    const f32x4u* p0 = (const f32x4u*)(x + (size_t)b * Cn * Nn);
    c0v = p0[tid];
    if (tid < 434) c1v = p0[tid + 1024];
  }
  for (int ck8 = 0; ck8 < 25; ++ck8) {
    f32x4 n0v = (f32x4){0.f, 0.f, 0.f, 0.f}, n1v = (f32x4){0.f, 0.f, 0.f, 0.f};
    if (ck8 < 24) {   // issue next chunk's loads (in flight across scatter)
      const f32x4u* pn = (const f32x4u*)(x + ((size_t)b * Cn + (ck8 + 1) * 8) * Nn);
      n0v = pn[tid];
      if (tid < 434) n1v = pn[tid + 1024];
    }
    __syncthreads();             // R free (prev scatter done)
    stage4[tid] = c0v;
    if (tid < 434) stage4[tid + 1024] = c1v;
    __syncthreads();             // stage visible
    {
      int m = tid >> 3, j = tid & 7;
      float val = 0.f;
      if (m < num1) val = stageF[j * Nn + (int)Mlist[m]];
      Pool[ck8 * (POOLR * 8) + m * 8 + j] = (short)f2bf(val);
    }
    c0v = n0v;
    c1v = n1v;
  }
  __syncthreads();   // pool complete

  // ---- persistent B-fragments: wave = (st = wv&7 -> 16 slots, rg = wv>>3 -> r-half) ----
  const int st = wv & 7;
  const int rg = wv >> 3;
  s16x8 bv[NCHUNK];
#pragma unroll
  for (int ck = 0; ck < NCHUNK; ++ck) {
    int chunk8 = ck * 4 + kg;    // 25..27 are zeroed chunks
    bv[ck] = *(const s16x8*)(Pool + chunk8 * (POOLR * 8) + (st * 16 + l16) * 8);
  }
  const int r0 = rg ? 5 : 0;
  const int nr = rg ? 4 : 5;

  // ---- 4 o-quarter passes: U-GEMM -> barrier -> gather+store -> barrier ----
  for (int g2 = 0; g2 < 4; ++g2) {
    for (int rr = 0; rr < nr; ++rr) {
      const int r = r0 + rr;
      const short* wp = Wt2 + ((size_t)r * OUTCn + g2 * 16 + l16) * 32 + kg * 8;
      f32x4 a = (f32x4){0.f, 0.f, 0.f, 0.f};
#pragma unroll
      for (int ck = 0; ck < NCHUNK; ++ck) {
        s16x8 av = *(const s16x8*)(wp + (size_t)ck * (9 * OUTCn * 32));
        a = __builtin_amdgcn_mfma_f32_16x16x32_bf16(av, bv[ck], a, 0, 0, 0);
      }
      // D: col(slot)=l16, row(o_local)=kg*4+q -> dwords kg*2, kg*2+1 of U row
      unsigned lo = ((unsigned)f2bf(a[0])) | (((unsigned)f2bf(a[1])) << 16);
      unsigned hi = ((unsigned)f2bf(a[2])) | (((unsigned)f2bf(a[3])) << 16);
      unsigned* ud = U + ((size_t)r * POOLR + st * 16 + l16) * USTDQ + kg * 2;
      ud[0] = lo;
      ud[1] = hi;
    }
    __syncthreads();   // U ready
    if (tid < Nn) {
      const int pi = tid / Pn, pj = tid - pi * Pn;
      const int base = pi * 29 + pj;
      float acc[16];
#pragma unroll
      for (int j = 0; j < 16; ++j) acc[j] = 0.f;
#pragma unroll
      for (int r = 0; r < 9; ++r) {
        int slot = Slot[base + (r / 3) * 29 + (r % 3)];
        const unsigned* u = U + ((size_t)r * POOLR + slot) * USTDQ;
#pragma unroll
        for (int d = 0; d < 8; ++d) {
          unsigned w = u[d];   // adjacent dwords -> ds_read2_b32; odd stride -> spread banks
          acc[d * 2 + 0] += __uint_as_float(w << 16);
          acc[d * 2 + 1] += __uint_as_float(w & 0xffff0000u);
        }
      }
      float* yb = y + ((size_t)b * OUTCn + g2 * 16) * Nn + tid;
#pragma unroll
      for (int j = 0; j < 16; ++j) yb[(size_t)j * Nn] = acc[j] + bias[g2 * 16 + j];
    }
    __syncthreads();   // U free for next pass
  }
}

extern "C" void kernel_launch(void* const* d_in, const int* in_sizes, int n_in,
                              void* d_out, int out_size, void* d_ws, size_t ws_size,
                              hipStream_t stream) {
  const float* x = (const float*)d_in[0];
  const float* W = (const float*)d_in[1];
  const float* bias = (const float*)d_in[2];
  const int* rand_idx = (const int*)d_in[3];
  float* y = (float*)d_out;

  short* Wt2 = (short*)d_ws;   // 258,048 B

  wprep_kernel<<<(WTOT + 255) / 256, 256, 0, stream>>>(W, Wt2);
  fat_kernel<<<Bn, 1024, 0, stream>>>(x, rand_idx, Wt2, bias, y);
}

// Round 17
// 147.981 us; speedup vs baseline: 1.0982x; 1.0982x over previous
//
#include <hip/hip_runtime.h>

#define Bn 512
#define Cn 202
#define Pn 27
#define Nn 729
#define CHn 200
#define Kn 58
#define OUTCn 64
#define CENTERn 364    // 13*27+13
#define NCHUNK 7
#define POOLR 128      // pool rows (slots); row 127 always zero
#define ZSLOT 127
#define NCK8 28        // 8-channel chunks in padded 224 (25 written; 25..27 read-but-A-zero)
#define MCAP 128
#define SPAD 864
#define WTOT (NCHUNK * 9 * OUTCn * 32)   // 129024 = 512 * 252
#define USTD 11        // U row stride in DWORDS (44 B; odd -> row starts cover all 32 banks)

typedef float f32x4 __attribute__((ext_vector_type(4)));
typedef f32x4 f32x4u __attribute__((aligned(4)));   // dword-aligned vector load
typedef short s16x8 __attribute__((ext_vector_type(8)));
typedef short s16x4 __attribute__((ext_vector_type(4)));

static __device__ __forceinline__ unsigned short f2bf(float f) {
  unsigned u = __float_as_uint(f);
  u += 0x7fffu + ((u >> 16) & 1u);   // RNE
  return (unsigned short)(u >> 16);
}

// ---------------- Kernel A: slot table + masked-pool list (parallel scan) + weight prep ----------------
__global__ __launch_bounds__(256) void src_kernel(const float* __restrict__ x,
                                                  const int* __restrict__ rand_idx,
                                                  const float* __restrict__ W,
                                                  short* __restrict__ slotpad_ws,
                                                  short* __restrict__ Mws,
                                                  int* __restrict__ num1_ws,
                                                  short* __restrict__ Wt2) {
  int b = blockIdx.x;
  __shared__ float sp[Nn];
  __shared__ short slotS[Nn];
  __shared__ short M[Nn];
  __shared__ int wsum[4];
  __shared__ int s_num;
  int tid = threadIdx.x;
  const int lane = tid & 63;
  const int wv = tid >> 6;
  const float* xsp = x + ((size_t)b * Cn + CHn) * Nn;
  for (int n = tid; n < Nn; n += 256) sp[n] = xsp[n];
  __syncthreads();
  float central = sp[CENTERn];
  __syncthreads();
  for (int k = tid; k < Kn; k += 256) sp[rand_idx[b * Kn + k]] = central;
  __syncthreads();

  int n0 = tid * 3;
  bool mk[3];
  int cnt = 0;
#pragma unroll
  for (int t = 0; t < 3; ++t) {
    int n = n0 + t;
    bool m = (n < Nn) && (sp[n] == central);
    mk[t] = m;
    cnt += m;
  }
  int v = cnt;
#pragma unroll
  for (int off = 1; off < 64; off <<= 1) {
    int u = __shfl_up(v, off);
    if (lane >= off) v += u;
  }
  if (lane == 63) wsum[wv] = v;
  __syncthreads();
  if (tid == 0) {
    int s = 0;
#pragma unroll
    for (int w = 0; w < 4; ++w) { int t = wsum[w]; wsum[w] = s; s += t; }
    s_num = s;
  }
  __syncthreads();
  int num = s_num;                       // >= 1 (central always masked)
  int excl = v - cnt + wsum[wv];
  int c = excl;
#pragma unroll
  for (int t = 0; t < 3; ++t) {
    int n = n0 + t;
    if (n < Nn) {
      if (mk[t]) { M[c] = (short)n; slotS[n] = (short)c; c++; }
      else { slotS[n] = (short)(~(n - c)); }   // zrank = n - (#masked before n)
    }
  }
  __syncthreads();

  int num1 = num < ZSLOT ? num : ZSLOT;
  if (tid == 0) num1_ws[b] = num1;
  for (int m = tid; m < MCAP; m += 256) Mws[(size_t)b * MCAP + m] = (m < num) ? M[m] : (short)0;
  for (int idx = tid; idx < 841; idx += 256) {
    int pi = idx / 29, pj = idx - pi * 29;
    short val = (short)ZSLOT;
    if (pi >= 1 && pi <= 27 && pj >= 1 && pj <= 27) {
      int n = (pi - 1) * Pn + (pj - 1);
      int s0 = slotS[n];
      int sv = (s0 >= 0) ? s0 : ((~s0) % num);
      if (sv > ZSLOT - 1) sv = ZSLOT - 1;   // freak-case clamp (num>127 is +6 sigma)
      val = (short)sv;
    }
    slotpad_ws[(size_t)b * SPAD + idx] = val;
  }

  // merged weight prep: block b converts elements [252b, 252b+252)
  if (tid < 252) {
    int idx = b * 252 + tid;
    int ck = idx / (9 * OUTCn * 32);
    int rem = idx - ck * (9 * OUTCn * 32);
    int r = rem / (OUTCn * 32);
    int rem2 = rem - r * (OUTCn * 32);
    int o = rem2 >> 5;
    int cl = rem2 & 31;
    int cc = ck * 32 + cl;
    float wval = (cc < CHn) ? W[((size_t)o * CHn + cc) * 9 + r] : 0.f;
    Wt2[idx] = (short)f2bf(wval);
  }
}

// ---------------- Kernel P: pool gather. grid (25, 512), vectorized + coalesced ----------------
__global__ __launch_bounds__(256) void pool_kernel(const float* __restrict__ x,
                                                   const short* __restrict__ Mws,
                                                   const int* __restrict__ num1_ws,
                                                   short* __restrict__ Pool_ws) {
  __shared__ __align__(16) float xs[8 * Nn];   // 23,328 B
  const int ck8 = blockIdx.x;     // 0..24 -> channels [8*ck8, 8*ck8+8), all < 200
  const int b = blockIdx.y;
  const int tid = threadIdx.x;
  const int c0 = ck8 * 8;
  const float* xp = x + ((size_t)b * Cn + c0) * Nn;

  const f32x4u* xp4 = (const f32x4u*)xp;
  f32x4* xs4 = (f32x4*)xs;
  for (int v = tid; v < (8 * Nn) / 4; v += 256) xs4[v] = xp4[v];
  __syncthreads();

  // all 256 threads: thread = (slot m, channel-quad cq); 8B stores, contiguous per wave-pair
  {
    const int m = tid >> 1;
    const int cq = tid & 1;
    const int num1 = num1_ws[b];
    bool valid = m < num1;
    int s = valid ? (int)Mws[(size_t)b * MCAP + m] : 0;
    s16x4 w4;
#pragma unroll
    for (int j = 0; j < 4; ++j) {
      float v = valid ? xs[(cq * 4 + j) * Nn + s] : 0.f;
      w4[j] = (short)f2bf(v);
    }
    *(s16x4*)(Pool_ws + ((size_t)b * NCK8 + ck8) * (POOLR * 8) + m * 8 + cq * 4) = w4;
  }
}

// ---------------- Kernel F2: fused U-GEMM + gather, o-quartered, odd-stride U ----------------
// grid (4, 512) = (o-quarter q, batch b), 512 thr = 8 waves, ~52.4 KB LDS (3 blocks/CU), ONE barrier.
// U rows at 11-DWORD stride (odd -> random-slot row starts cover all 32 banks, ~2-way = free).
// Phase 1: wave = (rg, stp): B-frags for 32 slots, Wt2 frags only for its 4-5 r's.
// Phase 2: per (pixel, tap) 8 dword reads -> ds_read2_b32, conflict-free.
__global__ __launch_bounds__(512) void fused2_kernel(const short* __restrict__ Wt2,
                                                     const short* __restrict__ Pool_ws,
                                                     const float* __restrict__ bias,
                                                     const short* __restrict__ slotpad_ws,
                                                     float* __restrict__ y) {
  __shared__ short Slot[841];                               //  1,682 B
  __shared__ __align__(16) unsigned int Ulds[9 * POOLR * USTD]; // 50,688 B
  const int q = blockIdx.x;       // o-quarter 0..3
  const int b = blockIdx.y;
  const int tid = threadIdx.x;
  const int lane = tid & 63;
  const int wv = tid >> 6;        // 0..7
  const int l16 = lane & 15;
  const int kg = lane >> 4;       // 0..3
  const int rg = wv >> 2;         // 0: r=0..4, 1: r=5..8
  const int stp = wv & 3;         // slot-pair: slots stp*32 .. stp*32+32

  for (int i2 = tid; i2 < 841; i2 += 512) Slot[i2] = slotpad_ws[(size_t)b * SPAD + i2];

  // ---- phase 1
  {
    const short* poolb = Pool_ws + (size_t)b * (NCK8 * POOLR * 8);
    const int slotA = stp * 32 + l16;
    s16x8 bvA[NCHUNK], bvB[NCHUNK];
#pragma unroll
    for (int ck = 0; ck < NCHUNK; ++ck) {
      const short* pb = poolb + ((size_t)(ck * 4 + kg) * POOLR + slotA) * 8;
      bvA[ck] = *(const s16x8*)(pb);
      bvB[ck] = *(const s16x8*)(pb + 16 * 8);
    }
    const int r0 = rg ? 5 : 0;
    const int nr = rg ? 4 : 5;
    for (int rr = 0; rr < nr; ++rr) {
      const int r = r0 + rr;
      const short* wp = Wt2 + ((size_t)r * OUTCn + q * 16 + l16) * 32 + kg * 8;
      f32x4 aA = (f32x4){0.f, 0.f, 0.f, 0.f};
      f32x4 aB = (f32x4){0.f, 0.f, 0.f, 0.f};
#pragma unroll
      for (int ck = 0; ck < NCHUNK; ++ck) {
        s16x8 av = *(const s16x8*)(wp + (size_t)ck * (9 * OUTCn * 32));
        aA = __builtin_amdgcn_mfma_f32_16x16x32_bf16(av, bvA[ck], aA, 0, 0, 0);
        aB = __builtin_amdgcn_mfma_f32_16x16x32_bf16(av, bvB[ck], aB, 0, 0, 0);
      }
      // D: col(slot)=l16 within tile, row(o_local)=kg*4+qq. Pack 4 bf16 -> 2 dwords.
      unsigned loA = ((unsigned)f2bf(aA[0])) | (((unsigned)f2bf(aA[1])) << 16);
      unsigned hiA = ((unsigned)f2bf(aA[2])) | (((unsigned)f2bf(aA[3])) << 16);
      unsigned loB = ((unsigned)f2bf(aB[0])) | (((unsigned)f2bf(aB[1])) << 16);
      unsigned hiB = ((unsigned)f2bf(aB[2])) | (((unsigned)f2bf(aB[3])) << 16);
      unsigned* uda = Ulds + ((size_t)r * POOLR + slotA) * USTD + kg * 2;
      uda[0] = loA;
      uda[1] = hiA;
      unsigned* udb = Ulds + ((size_t)r * POOLR + slotA + 16) * USTD + kg * 2;
      udb[0] = loB;
      udb[1] = hiB;
    }
  }
  __syncthreads();   // U + Slot ready

  // ---- phase 2: accumulate; thread t owns pixels n1=t and n2=t+512
  float accA[16], accB[16];
#pragma unroll
  for (int j = 0; j < 16; ++j) { accA[j] = 0.f; accB[j] = 0.f; }

  const int n1 = tid;
  const int pi1 = n1 / Pn, pj1 = n1 - pi1 * Pn;
  const int base1 = pi1 * 29 + pj1;
  const bool has2 = (tid + 512) < Nn;
  const int n2 = has2 ? (tid + 512) : n1;
  const int pi2 = n2 / Pn, pj2 = n2 - pi2 * Pn;
  const int base2 = pi2 * 29 + pj2;

#pragma unroll
  for (int r = 0; r < 9; ++r) {
    const int off = (r / 3) * 29 + (r % 3);
    {
      int slot = Slot[base1 + off];
      const unsigned* u = Ulds + ((size_t)r * POOLR + slot) * USTD;
#pragma unroll
      for (int d = 0; d < 8; ++d) {
        unsigned w = u[d];   // adjacent dwords -> ds_read2_b32; odd row stride -> no conflicts
        accA[d * 2 + 0] += __uint_as_float(w << 16);
        accA[d * 2 + 1] += __uint_as_float(w & 0xffff0000u);
      }
    }
    if (has2) {
      int slot = Slot[base2 + off];
      const unsigned* u = Ulds + ((size_t)r * POOLR + slot) * USTD;
#pragma unroll
      for (int d = 0; d < 8; ++d) {
        unsigned w = u[d];
        accB[d * 2 + 0] += __uint_as_float(w << 16);
        accB[d * 2 + 1] += __uint_as_float(w & 0xffff0000u);
      }
    }
  }

  // ---- stores: 16 o-planes, lanes consecutive n -> coalesced
  float* yb = y + ((size_t)b * OUTCn + q * 16) * Nn;
#pragma unroll
  for (int j = 0; j < 16; ++j) {
    float bo = bias[q * 16 + j];
    yb[(size_t)j * Nn + n1] = accA[j] + bo;
    if (has2) yb[(size_t)j * Nn + n2] = accB[j] + bo;
  }
}

extern "C" void kernel_launch(void* const* d_in, const int* in_sizes, int n_in,
                              void* d_out, int out_size, void* d_ws, size_t ws_size,
                              hipStream_t stream) {
  const float* x = (const float*)d_in[0];
  const float* W = (const float*)d_in[1];
  const float* bias = (const float*)d_in[2];
  const int* rand_idx = (const int*)d_in[3];
  float* y = (float*)d_out;

  char* p = (char*)d_ws;
  short* slotpad = (short*)p;   p += (size_t)Bn * SPAD * 2;               //    884,736
  short* Mws = (short*)p;       p += (size_t)Bn * MCAP * 2;               //    131,072
  int* num1 = (int*)p;          p += 2048;
  short* Wt2 = (short*)p;       p += (size_t)WTOT * 2;                    //    258,048
  short* Pool_ws = (short*)p;                                             // 29,360,128

  src_kernel<<<Bn, 256, 0, stream>>>(x, rand_idx, W, slotpad, Mws, num1, Wt2);
  pool_kernel<<<dim3(25, Bn), 256, 0, stream>>>(x, Mws, num1, Pool_ws);
  fused2_kernel<<<dim3(4, Bn), 512, 0, stream>>>(Wt2, Pool_ws, bias, slotpad, y);
}